// Round 9
// baseline (246.469 us; speedup 1.0000x reference)
//
#include <hip/hip_runtime.h>

#define NB 8      // batches
#define NT 16     // timesteps
#define NN 256    // points
#define NS 3      // scales

typedef float f32x4 __attribute__((ext_vector_type(4)));
typedef float f32x8 __attribute__((ext_vector_type(8)));
typedef int   i32x4 __attribute__((ext_vector_type(4)));

// ---------------------------------------------------------------------------
// Kernel 1: leader-clustering groups, ONE WAVE per batch, zero barriers.
// Bit-exact distance math (no fma contraction, correctly-rounded sqrt):
// group ids have zero error tolerance.
// ---------------------------------------------------------------------------
__global__ __launch_bounds__(64) void groups_kernel(
    const float* __restrict__ positions,
    float* __restrict__ out_groups_f,
    int* __restrict__ out_groups_i)
{
    const int b    = blockIdx.x;
    const int lane = threadIdx.x;

    const float2* __restrict__ P =
        ((const float2*)positions) + ((size_t)b * NT + (NT - 1)) * NN;

    float px[4], py[4];
#pragma unroll
    for (int k = 0; k < 4; ++k) {
        const float2 p = P[k * 64 + lane];
        px[k] = p.x; py[k] = p.y;
    }

    unsigned long long amask[4] = {0ull, 0ull, 0ull, 0ull};
    int grp[4] = {0, 0, 0, 0};
    int cur = 0;

#pragma unroll
    for (int ki = 0; ki < 4; ++ki) {
        for (int li = 0; li < 64; ++li) {
            if ((amask[ki] >> li) & 1ull) continue;
            const float pix = __shfl(px[ki], li);
            const float piy = __shfl(py[ki], li);
#pragma unroll
            for (int k = ki; k < 4; ++k) {
                const bool elig = (k > ki) || (lane >= li);
                const bool unas = (((amask[k] >> lane) & 1ull) == 0ull);
                const float dx = pix - px[k];
                const float dy = piy - py[k];
                const float sq = __fadd_rn(__fmul_rn(dx, dx), __fmul_rn(dy, dy));
                const float d  = (sq > 0.0f) ? __fsqrt_rn(sq) : 0.0f;
                const bool newly = elig && unas && (d <= 2.0f);
                const unsigned long long nb = __ballot(newly);
                amask[k] |= nb;
                if (newly) grp[k] = cur;
            }
            ++cur;
            if (!(~(amask[0] & amask[1] & amask[2] & amask[3]))) break;
        }
    }

#pragma unroll
    for (int k = 0; k < 4; ++k) {
        const int j = b * NN + k * 64 + lane;
        out_groups_i[j] = grp[k];
        out_groups_f[j] = (float)grp[k];
    }
}

// ---------------------------------------------------------------------------
// Kernel 2: DENSE GRID-STRIDE SWEEP over 1KB row-chunks.
// Evidence: every slab-partitioned layout (6-stream, sequential, staggered)
// ran at ~3.0-3.2 TB/s write BW, while the grid-stride rocclr fill hits
// 6.6 TB/s on the same buffers. Remaining structural difference: the fill's
// instantaneous active-address set is one dense contiguous window marching
// across the buffer; slab layouts scatter ~6K cursors over all 201.6 MB
// (HBM row-locality per bank destroyed). Here: chunk c = one 1KB row of one
// (tensor,plane); wave w writes chunks k*6144+w -> iteration k's active set
// is one contiguous 6MB window. Point data loaded per-iteration from
// global (520KB working set, L1/L2-resident; ~7 TB/s L2 read demand vs
// 34.5 ceiling; VALU ~12us vs 32us floor - stays write-bound).
// ---------------------------------------------------------------------------
#define TOTAL_CHUNKS (2 * NB * NS * NT * NN)    // 196608
#define SWEEP_BLOCKS 1536
#define SWEEP_WAVES  (SWEEP_BLOCKS * 4)         // 6144
#define ITERS (TOTAL_CHUNKS / SWEEP_WAVES)      // 32

__global__ __launch_bounds__(256) void adj_sweep(
    const float* __restrict__ positions,
    const float* __restrict__ displacements,
    const int*   __restrict__ groups,
    float* __restrict__ out)                    // d_out base
{
    const int wid  = blockIdx.x * 4 + (threadIdx.x >> 6);   // 0..6143
    const int lane = threadIdx.x & 63;

    const size_t ADJ_F  = (size_t)NB * NS * NT * NN * NN;   // 25,165,824 floats
    const size_t INTRA0 = ADJ_F + (size_t)NB * NN;          // intra base (skip groups)

    for (int k = 0; k < ITERS; ++k) {
        const int chunk = k * SWEEP_WAVES + wid;
        const int isIn  = (chunk >= TOTAL_CHUNKS / 2) ? 1 : 0;
        const int pc    = isIn ? (chunk - TOTAL_CHUNKS / 2) : chunk;
        const int plane = pc >> 8;        // (b*3+s)*16 + t
        const int i     = pc & 255;       // row
        const int t     = plane & 15;
        const int bs    = plane >> 4;     // b*3 + s
        const int s     = bs % 3;         // magic-mul, cheap
        const int b     = bs / 3;
        const int pbase = (b * NT + t) * NN;

        // lane's 4 columns j = 4*lane..4*lane+3: (x,y) interleaved -> 32B load
        const f32x8 pj = *(const f32x8*)(positions     + (size_t)(pbase + 4 * lane) * 2);
        const f32x8 uj = *(const f32x8*)(displacements + (size_t)(pbase + 4 * lane) * 2);
        const i32x4 gj = *(const i32x4*)(groups + b * NN + 4 * lane);

        // wave-uniform row values (broadcast loads)
        const float2 pi = *(const float2*)(positions     + (size_t)(pbase + i) * 2);
        const float2 ui = *(const float2*)(displacements + (size_t)(pbase + i) * 2);
        const int    gi = groups[b * NN + i];

        const float S = (s == 0) ? 0.5f : ((s == 1) ? 1.0f : 2.0f);

        f32x4 V;
#pragma unroll
        for (int cc = 0; cc < 4; ++cc) {
            const float dx = pi.x - pj[2 * cc];
            const float dy = pi.y - pj[2 * cc + 1];
            const float sq = __fadd_rn(__fmul_rn(dx, dx), __fmul_rn(dy, dy));
            const float d  = __fsqrt_rn(sq);        // exact; sqrt(0)=0 matches ref

            const float ex = ui.x - uj[2 * cc];
            const float ey = ui.y - uj[2 * cc + 1];
            const float sqe = __fadd_rn(__fmul_rn(ex, ex), __fmul_rn(ey, ey));
            const float dn  = __builtin_amdgcn_sqrtf(sqe);
            const float w   = __builtin_amdgcn_rcpf(dn + 1e-6f);

            const float gmv = (gi == gj[cc]) ? 1.0f : 0.0f;
            const float fac = isIn ? gmv : 1.0f;
            V[cc] = (d <= S) ? w * fac : 0.0f;
        }

        const size_t dst = (isIn ? INTRA0 + (size_t)pc * NN
                                 : (size_t)pc * NN) + 4 * lane;
        *(f32x4*)(out + dst) = V;
    }
}

extern "C" void kernel_launch(void* const* d_in, const int* in_sizes, int n_in,
                              void* d_out, int out_size, void* d_ws, size_t ws_size,
                              hipStream_t stream) {
    const float* positions     = (const float*)d_in[0];
    const float* displacements = (const float*)d_in[1];
    float* out = (float*)d_out;

    const size_t ADJ_ELEMS = (size_t)NB * NS * NT * NN * NN;  // 25,165,824
    float* groups_f = out + ADJ_ELEMS;
    int*   groups_i = (int*)d_ws;

    groups_kernel<<<NB, 64, 0, stream>>>(positions, groups_f, groups_i);
    adj_sweep<<<SWEEP_BLOCKS, 256, 0, stream>>>(positions, displacements,
                                                groups_i, out);
}

// Round 10
// 218.305 us; speedup vs baseline: 1.1290x; 1.1290x over previous
//
#include <hip/hip_runtime.h>

#define NB 8      // batches
#define NT 16     // timesteps
#define NN 256    // points
#define NS 3      // scales

typedef float f32x4 __attribute__((ext_vector_type(4)));
typedef int   i32x4 __attribute__((ext_vector_type(4)));

// ---------------------------------------------------------------------------
// Kernel 1: leader-clustering groups, ONE WAVE per batch, zero barriers.
// Bit-exact distance math (no fma contraction, correctly-rounded sqrt):
// group ids have zero error tolerance.
// ---------------------------------------------------------------------------
__global__ __launch_bounds__(64) void groups_kernel(
    const float* __restrict__ positions,
    float* __restrict__ out_groups_f,
    int* __restrict__ out_groups_i)
{
    const int b    = blockIdx.x;
    const int lane = threadIdx.x;

    const float2* __restrict__ P =
        ((const float2*)positions) + ((size_t)b * NT + (NT - 1)) * NN;

    float px[4], py[4];
#pragma unroll
    for (int k = 0; k < 4; ++k) {
        const float2 p = P[k * 64 + lane];
        px[k] = p.x; py[k] = p.y;
    }

    unsigned long long amask[4] = {0ull, 0ull, 0ull, 0ull};
    int grp[4] = {0, 0, 0, 0};
    int cur = 0;

#pragma unroll
    for (int ki = 0; ki < 4; ++ki) {
        for (int li = 0; li < 64; ++li) {
            if ((amask[ki] >> li) & 1ull) continue;
            const float pix = __shfl(px[ki], li);
            const float piy = __shfl(py[ki], li);
#pragma unroll
            for (int k = ki; k < 4; ++k) {
                const bool elig = (k > ki) || (lane >= li);
                const bool unas = (((amask[k] >> lane) & 1ull) == 0ull);
                const float dx = pix - px[k];
                const float dy = piy - py[k];
                const float sq = __fadd_rn(__fmul_rn(dx, dx), __fmul_rn(dy, dy));
                const float d  = (sq > 0.0f) ? __fsqrt_rn(sq) : 0.0f;
                const bool newly = elig && unas && (d <= 2.0f);
                const unsigned long long nb = __ballot(newly);
                amask[k] |= nb;
                if (newly) grp[k] = cur;
            }
            ++cur;
            if (!(~(amask[0] & amask[1] & amask[2] & amask[3]))) break;
        }
    }

#pragma unroll
    for (int k = 0; k < 4; ++k) {
        const int j = b * NN + k * 64 + lane;
        out_groups_i[j] = grp[k];
        out_groups_f[j] = (float)grp[k];
    }
}

// ---------------------------------------------------------------------------
// Kernel 2: adjacency + intra — R5 structure + REGISTER-BUFFERED 4KB BURSTS.
// Evidence: all layouts (6-stream, seq, staggered, dense) sit at ~3.3 TB/s
// while rocclr's fill (few waves, long sequential store runs) hits 6.6 TB/s.
// Surviving theory: per-CU outgoing write stream round-robins ~24 cursors at
// 1KB granularity -> DRAM row thrash. Fix: buffer 4 consecutive rows x 6
// outputs in registers, then issue 24 stores STREAM-MAJOR = six 4KB
// contiguous bursts per visit. Wave owns 8 contiguous rows. ~160 VGPR ->
// ~12 waves/CU (also fill-like). Single-pass compute (VALU ~14us, floor 31).
// ---------------------------------------------------------------------------
#define CHUNKS 8

__global__ __launch_bounds__(256) void adj_kernel(
    const float* __restrict__ positions,
    const float* __restrict__ displacements,
    const int* __restrict__ groups,
    float* __restrict__ adj,
    float* __restrict__ intra)
{
    __shared__ float px[NN], py[NN], ux[NN], uy[NN];
    __shared__ int grp[NN];

    const int blk = blockIdx.x;          // b*T*CHUNKS + t*CHUNKS + c
    const int c   = blk & 7;
    const int bt  = blk >> 3;
    const int t   = bt & 15;
    const int b   = bt >> 4;
    const int tid = threadIdx.x;

    {
        const float2 p = ((const float2*)positions)[((size_t)b * NT + t) * NN + tid];
        const float2 u = ((const float2*)displacements)[((size_t)b * NT + t) * NN + tid];
        px[tid] = p.x;  py[tid] = p.y;
        ux[tid] = u.x;  uy[tid] = u.y;
        grp[tid] = groups[b * NN + tid];
    }
    __syncthreads();

    const int cl = tid & 63;   // column quad: cols 4*cl..4*cl+3
    const int rw = tid >> 6;   // wave id: owns rows c*32 + rw*8 .. +8

    const f32x4 pxj = ((const f32x4*)px)[cl];
    const f32x4 pyj = ((const f32x4*)py)[cl];
    const f32x4 uxj = ((const f32x4*)ux)[cl];
    const f32x4 uyj = ((const f32x4*)uy)[cl];
    const i32x4 gj  = ((const i32x4*)grp)[cl];

    const size_t splane  = (size_t)NT * NN * NN;
    const size_t base_bt = ((size_t)(b * NS) * NT + t) * (size_t)(NN * NN);

    const int r0 = c * 32 + rw * 8;

#pragma unroll
    for (int g = 0; g < 2; ++g) {
        f32x4 A0[4], A1[4], A2[4], I0[4], I1[4], I2[4];

#pragma unroll
        for (int r = 0; r < 4; ++r) {
            const int i = r0 + g * 4 + r;           // wave-uniform row
            const float pix = px[i], piy = py[i];
            const float uix = ux[i], uiy = uy[i];
            const int   gi  = grp[i];

#pragma unroll
            for (int cc = 0; cc < 4; ++cc) {
                const float dx = pix - pxj[cc];
                const float dy = piy - pyj[cc];
                const float sq = __fadd_rn(__fmul_rn(dx, dx), __fmul_rn(dy, dy));
                const float d  = __fsqrt_rn(sq);    // exact; sqrt(0)=0 matches ref

                const float ex = uix - uxj[cc];
                const float ey = uiy - uyj[cc];
                const float sqe = __fadd_rn(__fmul_rn(ex, ex), __fmul_rn(ey, ey));
                const float dn  = __builtin_amdgcn_sqrtf(sqe);
                const float w   = __builtin_amdgcn_rcpf(dn + 1e-6f);

                const float gm = (gi == gj[cc]) ? 1.0f : 0.0f;
                const float a0 = (d <= 0.5f) ? w : 0.0f;
                const float a1 = (d <= 1.0f) ? w : 0.0f;
                const float a2 = (d <= 2.0f) ? w : 0.0f;

                A0[r][cc] = a0;       A1[r][cc] = a1;       A2[r][cc] = a2;
                I0[r][cc] = a0 * gm;  I1[r][cc] = a1 * gm;  I2[r][cc] = a2 * gm;
            }
        }

        // stream-major stores: six bursts of 4 consecutive 1KB rows (4KB each)
        const size_t off0 = base_bt + (size_t)(r0 + g * 4) * NN + 4 * cl;
#pragma unroll
        for (int r = 0; r < 4; ++r) *(f32x4*)(adj + off0 + (size_t)r * NN) = A0[r];
#pragma unroll
        for (int r = 0; r < 4; ++r) *(f32x4*)(adj + splane + off0 + (size_t)r * NN) = A1[r];
#pragma unroll
        for (int r = 0; r < 4; ++r) *(f32x4*)(adj + 2 * splane + off0 + (size_t)r * NN) = A2[r];
#pragma unroll
        for (int r = 0; r < 4; ++r) *(f32x4*)(intra + off0 + (size_t)r * NN) = I0[r];
#pragma unroll
        for (int r = 0; r < 4; ++r) *(f32x4*)(intra + splane + off0 + (size_t)r * NN) = I1[r];
#pragma unroll
        for (int r = 0; r < 4; ++r) *(f32x4*)(intra + 2 * splane + off0 + (size_t)r * NN) = I2[r];
    }
}

extern "C" void kernel_launch(void* const* d_in, const int* in_sizes, int n_in,
                              void* d_out, int out_size, void* d_ws, size_t ws_size,
                              hipStream_t stream) {
    const float* positions     = (const float*)d_in[0];
    const float* displacements = (const float*)d_in[1];
    float* out = (float*)d_out;

    const size_t ADJ_ELEMS = (size_t)NB * NS * NT * NN * NN;  // 25,165,824
    float* adj      = out;
    float* groups_f = out + ADJ_ELEMS;
    float* intra    = out + ADJ_ELEMS + (size_t)NB * NN;
    int*   groups_i = (int*)d_ws;

    groups_kernel<<<NB, 64, 0, stream>>>(positions, groups_f, groups_i);
    adj_kernel<<<NB * NT * CHUNKS, NN, 0, stream>>>(positions, displacements,
                                                    groups_i, adj, intra);
}